// Round 1
// baseline (1203.890 us; speedup 1.0000x reference)
//
#include <hip/hip_runtime.h>

#define TPB 256

__device__ __forceinline__ float wave_sum(float v){
  #pragma unroll
  for (int off=32; off>0; off>>=1) v += __shfl_xor(v, off, 64);
  return v;
}

__device__ __forceinline__ int wave_incl_scan(int v, int lane){
  #pragma unroll
  for (int off=1; off<64; off<<=1){
    int u = __shfl_up(v, off, 64);
    if (lane >= off) v += u;
  }
  return v;
}

// ---------------- CSR build ----------------
__global__ __launch_bounds__(TPB) void count_k(const int* __restrict__ dstE, int* __restrict__ cnt, int E){
  int e = blockIdx.x*TPB + threadIdx.x;
  if (e < E) atomicAdd(&cnt[dstE[e]], 1);
}

__global__ __launch_bounds__(TPB) void dis_k(const int* __restrict__ cnt, float* __restrict__ disp, int nN){
  int n = blockIdx.x*TPB + threadIdx.x;
  if (n < nN) disp[n] = rsqrtf((float)cnt[n] + 1.0f);   // deg includes self-loop
}

__global__ __launch_bounds__(TPB) void scan1_k(const int* __restrict__ cnt, int* __restrict__ rowptr,
                                               int* __restrict__ bsum, int nN){
  int t = threadIdx.x;
  int i = blockIdx.x*TPB + t;
  int lane = t & 63, wid = t >> 6;
  int v = (i < nN) ? cnt[i] : 0;
  int inc = wave_incl_scan(v, lane);
  __shared__ int wsum[4];
  if (lane == 63) wsum[wid] = inc;
  __syncthreads();
  int off = 0;
  #pragma unroll
  for (int w=0; w<4; ++w) if (w < wid) off += wsum[w];
  if (i < nN) rowptr[i] = inc - v + off;
  if (t == 0) bsum[blockIdx.x] = wsum[0]+wsum[1]+wsum[2]+wsum[3];
}

__global__ __launch_bounds__(TPB) void scan2_k(int* __restrict__ bsum, int nbk){
  int t = threadIdx.x;
  int lane = t & 63, wid = t >> 6;
  int v = (t < nbk) ? bsum[t] : 0;
  int inc = wave_incl_scan(v, lane);
  __shared__ int wsum[4];
  if (lane == 63) wsum[wid] = inc;
  __syncthreads();
  int off = 0;
  #pragma unroll
  for (int w=0; w<4; ++w) if (w < wid) off += wsum[w];
  __syncthreads();
  if (t < nbk) bsum[t] = inc - v + off;
}

__global__ __launch_bounds__(TPB) void scan3_k(int* __restrict__ rowptr, const int* __restrict__ bsum, int nN, int E){
  int i = blockIdx.x*TPB + threadIdx.x;
  if (i < nN) rowptr[i] += bsum[blockIdx.x];
  if (i == 0) rowptr[nN] = E;
}

__global__ __launch_bounds__(TPB) void fill_k(const int* __restrict__ srcE, const int* __restrict__ dstE,
                                              const int* __restrict__ rowptr, int* __restrict__ cursor,
                                              int* __restrict__ csr, int E){
  int e = blockIdx.x*TPB + threadIdx.x;
  if (e >= E) return;
  int d = dstE[e];
  int pos = atomicAdd(&cursor[d], 1);
  csr[rowptr[d] + pos] = srcE[e];
}

// ---------------- LayerNorm stats (wave per node) ----------------
__global__ __launch_bounds__(TPB) void ln128_k(const float* __restrict__ base, int stride,
                                               float* __restrict__ meanp, float* __restrict__ rstdp, int nN){
  int g = blockIdx.x*TPB + threadIdx.x;
  int n = g >> 6, lane = g & 63;
  if (n >= nN) return;
  const float* p = base + (size_t)n*stride;
  float v0 = p[lane], v1 = p[lane+64];
  float s  = wave_sum(v0+v1);
  float sq = wave_sum(v0*v0+v1*v1);
  float m = s * (1.f/128.f);
  float var = fmaxf(sq * (1.f/128.f) - m*m, 0.f);
  if (lane == 0){ meanp[n] = m; rstdp[n] = rsqrtf(var + 1e-5f); }
}

__global__ __launch_bounds__(TPB) void ln512_k(const float* __restrict__ x, const float* __restrict__ hbuf,
                                               float* __restrict__ meanp, float* __restrict__ rstdp, int nN){
  int g = blockIdx.x*TPB + threadIdx.x;
  int n = g >> 6, lane = g & 63;
  if (n >= nN) return;
  float s = 0.f, sq = 0.f;
  #pragma unroll
  for (int k=0;k<8;k++){
    int d = lane + k*64;
    float v = (d < 128) ? x[(size_t)n*128 + d] : hbuf[(size_t)n*384 + (d-128)];
    s += v; sq += v*v;
  }
  s = wave_sum(s); sq = wave_sum(sq);
  float m = s * (1.f/512.f);
  float var = fmaxf(sq * (1.f/512.f) - m*m, 0.f);
  if (lane == 0){ meanp[n] = m; rstdp[n] = rsqrtf(var + 1e-5f); }
}

// ---------------- combined weight transpose: wcomb[(d*5+g)*OUT + j] ----------------
// g in 0..3 -> sw[j, d*4+g] ; g==4 -> bw[j, d]
__global__ __launch_bounds__(TPB) void prep_w_k(const float* __restrict__ sw, const float* __restrict__ bw,
                                                float* __restrict__ wcomb, int IN, int OUT){
  int idx = blockIdx.x*TPB + threadIdx.x;
  if (idx >= IN*5*OUT) return;
  int j = idx % OUT, k = idx / OUT;
  int d = k / 5, g2 = k % 5;
  wcomb[idx] = (g2 < 4) ? sw[(size_t)j*IN*4 + d*4 + g2] : bw[(size_t)j*IN + d];
}

// ---------------- fused FKAN GEMM ----------------
// out[n,j] = sum_d sum_g basis(ln(h[n,d]))_g * sw[j,d*4+g] + silu(h[n,d])*bw[j,d] + bias[j]
template<int IN, int OUT, int NB, int TM, int TN>
__global__ __launch_bounds__(TPB) void fkan_gemm_k(
    const float* __restrict__ in0, int s0, int w0,
    const float* __restrict__ in1, int s1,
    const float* __restrict__ meanp, const float* __restrict__ rstdp,
    const float* __restrict__ lng, const float* __restrict__ lnb,
    const float* __restrict__ wcomb, const float* __restrict__ bias,
    float* __restrict__ outp, int ostride, int nN)
{
  constexpr int KC = 16;              // input dims per chunk
  constexpr int KP = KC*5;            // combined K per chunk (4 basis + 1 silu per dim)
  constexpr int FT_LD = NB + 4;       // pad to keep ds_read conflicts <=2-way
  constexpr int NG = NB / TM;         // node groups
  __shared__ __align__(16) float Ft[KP][FT_LD];
  __shared__ __align__(16) float Wt[KP][OUT];
  __shared__ float smean[NB], srstd[NB];
  const int t = threadIdx.x;
  const int nb0 = blockIdx.x * NB;
  for (int i=t; i<NB; i+=TPB){
    int n = nb0 + i; bool ok = n < nN;
    smean[i] = ok ? meanp[n] : 0.f;
    srstd[i] = ok ? rstdp[n] : 0.f;
  }
  const int tmg = t % NG;
  const int tng = t / NG;
  const float gridv[4] = {-2.f, -2.f/3.f, 2.f/3.f, 2.f};   // linspace(-2,2,4); 1/DENOM = 0.75
  float acc[TM][TN];
  #pragma unroll
  for (int a=0;a<TM;a++)
    #pragma unroll
    for (int b=0;b<TN;b++) acc[a][b]=0.f;

  for (int c=0; c<IN/KC; ++c){
    const int d0 = c*KC;
    __syncthreads();
    // ---- build F tile (LN -> RBF basis + silu), k-major [KP][NB]
    #pragma unroll
    for (int q=t; q<NB*(KC/4); q+=TPB){
      int node = q / (KC/4);
      int f4   = q % (KC/4);
      int n = nb0 + node;
      int d = d0 + f4*4;
      float4 hv = make_float4(0.f,0.f,0.f,0.f);
      if (n < nN){
        hv = (d < w0) ? *(const float4*)(in0 + (size_t)n*s0 + d)
                      : *(const float4*)(in1 + (size_t)n*s1 + (d - w0));
      }
      float m = smean[node], r = srstd[node];
      const float* hvp = (const float*)&hv;
      #pragma unroll
      for (int u=0;u<4;++u){
        int dd = f4*4 + u;
        float v = hvp[u];
        float xn = (v - m)*r*lng[d0+dd] + lnb[d0+dd];
        #pragma unroll
        for (int g2=0; g2<4; ++g2){
          float z = (xn - gridv[g2]) * 0.75f;
          Ft[dd*5+g2][node] = __expf(-z*z);
        }
        Ft[dd*5+4][node] = v / (1.f + __expf(-v));   // silu on pre-LN input
      }
    }
    // ---- stage W tile (coalesced; wcomb is pre-transposed k-major)
    {
      const float4* wsrc = (const float4*)(wcomb + (size_t)d0*5*OUT);
      float4* wdst = (float4*)(&Wt[0][0]);
      #pragma unroll
      for (int q=t; q<KP*OUT/4; q+=TPB) wdst[q] = wsrc[q];
    }
    __syncthreads();
    // ---- register-tiled f32 MAC
    #pragma unroll 4
    for (int k=0; k<KP; ++k){
      float a[TM];
      *(float4*)a = *(const float4*)&Ft[k][tmg*TM];   // TM==4
      float b[TN];
      #pragma unroll
      for (int nn=0; nn<TN; ++nn) b[nn] = Wt[k][tng*TN + nn];
      #pragma unroll
      for (int mm=0; mm<TM; ++mm)
        #pragma unroll
        for (int nn=0; nn<TN; ++nn)
          acc[mm][nn] = fmaf(a[mm], b[nn], acc[mm][nn]);
    }
  }
  #pragma unroll
  for (int mm=0; mm<TM; ++mm){
    int n = nb0 + tmg*TM + mm;
    if (n < nN){
      #pragma unroll
      for (int nn=0; nn<TN; ++nn){
        outp[(size_t)n*ostride + tng*TN + nn] = acc[mm][nn] + bias[tng*TN+nn];
      }
    }
  }
}

// ---------------- GCN aggregation (gather via CSR, wave per node) ----------------
__global__ __launch_bounds__(TPB) void gcn_k(const float* __restrict__ hsrc, const int* __restrict__ rowptr,
                                             const int* __restrict__ csr, const float* __restrict__ disp,
                                             float* __restrict__ outb, int nN){
  int g = blockIdx.x*TPB + threadIdx.x;
  int n = g >> 6, lane = g & 63;
  if (n >= nN) return;
  int e0 = rowptr[n], e1 = rowptr[n+1];
  float dn = disp[n];
  float ax=0.f, ay=0.f;
  for (int e=e0; e<e1; ++e){
    int s = csr[e];
    float w = disp[s];
    float2 hv = *(const float2*)(hsrc + (size_t)s*128 + 2*lane);
    ax = fmaf(hv.x, w, ax); ay = fmaf(hv.y, w, ay);
  }
  float2 hn = *(const float2*)(hsrc + (size_t)n*128 + 2*lane);
  ax = (ax + hn.x*dn) * dn;     // self-loop term + final dis[n] factor
  ay = (ay + hn.y*dn) * dn;
  float2 r2; r2.x = ax; r2.y = ay;
  *(float2*)(outb + (size_t)n*384 + 2*lane) = r2;
}

// ---------------- BatchNorm ----------------
__global__ __launch_bounds__(TPB) void bn_stat_k(const float* __restrict__ hb, float* __restrict__ stats, int nN){
  int col  = threadIdx.x & 127;
  int half = threadIdx.x >> 7;
  float s=0.f, sq=0.f;
  for (int r = blockIdx.x*2 + half; r < nN; r += gridDim.x*2){
    float v = hb[(size_t)r*384 + col];
    s += v; sq += v*v;
  }
  __shared__ float ls[TPB], lq[TPB];
  ls[threadIdx.x]=s; lq[threadIdx.x]=sq;
  __syncthreads();
  if (half==0){
    s  = ls[threadIdx.x] + ls[threadIdx.x+128];
    sq = lq[threadIdx.x] + lq[threadIdx.x+128];
    atomicAdd(&stats[col], s);
    atomicAdd(&stats[128+col], sq);
  }
}

__global__ void bn_fin_k(const float* __restrict__ stats, const float* __restrict__ g, const float* __restrict__ b,
                         float* __restrict__ scsh, int nN){
  int c = threadIdx.x;
  float inv = 1.f/(float)nN;
  float m = stats[c]*inv;
  float var = fmaxf(stats[128+c]*inv - m*m, 0.f);
  float sc = g[c]*rsqrtf(var + 1e-5f);
  scsh[c] = sc;
  scsh[128+c] = b[c] - m*sc;
}

__global__ __launch_bounds__(TPB) void bn_apply_k(float* __restrict__ hb, const float* __restrict__ scsh, int nN){
  int idx = blockIdx.x*TPB + threadIdx.x;
  if (idx >= nN*128) return;
  int n = idx >> 7, c = idx & 127;
  float* p = hb + (size_t)n*384 + c;
  *p = fmaf(*p, scsh[c], scsh[128+c]);
}

extern "C" void kernel_launch(void* const* d_in, const int* in_sizes, int n_in,
                              void* d_out, int out_size, void* d_ws, size_t ws_size,
                              hipStream_t stream)
{
  const float* x        = (const float*)d_in[0];
  const int*   ei       = (const int*)d_in[1];
  const float* ln_g     = (const float*)d_in[2];
  const float* ln_b     = (const float*)d_in[3];
  const float* sw       = (const float*)d_in[4];
  const float* bw       = (const float*)d_in[5];
  const float* bb       = (const float*)d_in[6];
  // d_in[7] gcn_bias: per-feature constant added right before BatchNorm ->
  // exactly canceled by BN's mean subtraction (variance unchanged). Skipped.
  const float* bn_g     = (const float*)d_in[8];
  const float* bn_b     = (const float*)d_in[9];
  const float* ln_g_out = (const float*)d_in[10];
  const float* ln_b_out = (const float*)d_in[11];
  const float* sw_out   = (const float*)d_in[12];
  const float* bw_out   = (const float*)d_in[13];
  const float* bb_out   = (const float*)d_in[14];
  float* out = (float*)d_out;

  const int nN = in_sizes[0] / 128;    // 50000
  const int E  = in_sizes[1] / 2;      // 800000

  // workspace layout
  char* ws = (char*)d_ws;
  size_t off = 0;
  auto alloc = [&](size_t bytes)->char*{
    char* p = ws + off; off = (off + bytes + 255) & ~size_t(255); return p;
  };
  float* hbuf  = (float*)alloc((size_t)nN*384*4);   // [N, 3*128] BN outputs (concat tail)
  float* tmp   = (float*)alloc((size_t)nN*128*4);   // FKAN output before GCN
  float* meanp = (float*)alloc((size_t)nN*4);
  float* rstdp = (float*)alloc((size_t)nN*4);
  float* disp  = (float*)alloc((size_t)nN*4);
  float* stats = (float*)alloc(256*4);
  float* scsh  = (float*)alloc(256*4);
  float* wcomb = (float*)alloc((size_t)2560*40*4 > (size_t)640*128*4 ? (size_t)2560*40*4 : (size_t)640*128*4);
  int* cnt     = (int*)alloc((size_t)nN*4);
  int* cursor  = (int*)alloc((size_t)nN*4);
  int* rowptr  = (int*)alloc((size_t)(nN+1)*4);
  int* bsum    = (int*)alloc(256*4);
  int* csr     = (int*)alloc((size_t)E*4);
  (void)ws_size; (void)n_in; (void)out_size;

  const int* srcE = ei;
  const int* dstE = ei + E;

  hipMemsetAsync(cnt, 0, (size_t)nN*4, stream);
  hipMemsetAsync(cursor, 0, (size_t)nN*4, stream);

  const int nbE = (E + TPB-1)/TPB;
  const int nbN = (nN + TPB-1)/TPB;     // 196
  count_k<<<nbE, TPB, 0, stream>>>(dstE, cnt, E);
  dis_k<<<nbN, TPB, 0, stream>>>(cnt, disp, nN);
  scan1_k<<<nbN, TPB, 0, stream>>>(cnt, rowptr, bsum, nN);
  scan2_k<<<1, TPB, 0, stream>>>(bsum, nbN);
  scan3_k<<<nbN, TPB, 0, stream>>>(rowptr, bsum, nN, E);
  fill_k<<<nbE, TPB, 0, stream>>>(srcE, dstE, rowptr, cursor, csr, E);

  const int nbW = (nN*64 + TPB-1)/TPB;  // wave-per-node kernels

  for (int i=0; i<3; ++i){
    const float* inbase = (i==0) ? x : (hbuf + (size_t)(i-1)*128);
    int instride = (i==0) ? 128 : 384;
    ln128_k<<<nbW, TPB, 0, stream>>>(inbase, instride, meanp, rstdp, nN);
    prep_w_k<<<(128*5*128 + TPB-1)/TPB, TPB, 0, stream>>>(
        sw + (size_t)i*128*512, bw + (size_t)i*128*128, wcomb, 128, 128);
    fkan_gemm_k<128,128,64,4,8><<<(nN+63)/64, TPB, 0, stream>>>(
        inbase, instride, 128, (const float*)nullptr, 0,
        meanp, rstdp, ln_g + (size_t)i*128, ln_b + (size_t)i*128,
        wcomb, bb + (size_t)i*128, tmp, 128, nN);
    gcn_k<<<nbW, TPB, 0, stream>>>(tmp, rowptr, csr, disp, hbuf + (size_t)i*128, nN);
    hipMemsetAsync(stats, 0, 256*4, stream);
    bn_stat_k<<<256, TPB, 0, stream>>>(hbuf + (size_t)i*128, stats, nN);
    bn_fin_k<<<1, 128, 0, stream>>>(stats, bn_g + (size_t)i*128, bn_b + (size_t)i*128, scsh, nN);
    bn_apply_k<<<(nN*128 + TPB-1)/TPB, TPB, 0, stream>>>(hbuf + (size_t)i*128, scsh, nN);
  }

  // final FKAN on concat [x | hbuf]  (512 -> 40)
  ln512_k<<<nbW, TPB, 0, stream>>>(x, hbuf, meanp, rstdp, nN);
  prep_w_k<<<(512*5*40 + TPB-1)/TPB, TPB, 0, stream>>>(sw_out, bw_out, wcomb, 512, 40);
  fkan_gemm_k<512,40,128,4,5><<<(nN+127)/128, TPB, 0, stream>>>(
      x, 128, 128, hbuf, 384,
      meanp, rstdp, ln_g_out, ln_b_out,
      wcomb, bb_out, out, 40, nN);
}

// Round 2
// 699.850 us; speedup vs baseline: 1.7202x; 1.7202x over previous
//
#include <hip/hip_runtime.h>

#define TPB 256

typedef __attribute__((ext_vector_type(8))) short s8v;     // 8 bf16 (4 VGPR) MFMA A/B frag
typedef __attribute__((ext_vector_type(4))) float f32x4;   // MFMA C/D frag
typedef __attribute__((ext_vector_type(4))) unsigned short us4;
typedef unsigned short u16;

__device__ __forceinline__ u16 f2bf(float f){
  unsigned u = __float_as_uint(f);
  u += 0x7fff + ((u >> 16) & 1);       // round-to-nearest-even
  return (u16)(u >> 16);
}

__device__ __forceinline__ float wave_sum(float v){
  #pragma unroll
  for (int off=32; off>0; off>>=1) v += __shfl_xor(v, off, 64);
  return v;
}

__device__ __forceinline__ int wave_incl_scan(int v, int lane){
  #pragma unroll
  for (int off=1; off<64; off<<=1){
    int u = __shfl_up(v, off, 64);
    if (lane >= off) v += u;
  }
  return v;
}

// ---------------- CSR build ----------------
__global__ __launch_bounds__(TPB) void count_k(const int* __restrict__ dstE, int* __restrict__ cnt, int E){
  int e = blockIdx.x*TPB + threadIdx.x;
  if (e < E) atomicAdd(&cnt[dstE[e]], 1);
}

__global__ __launch_bounds__(TPB) void dis_k(const int* __restrict__ cnt, float* __restrict__ disp, int nN){
  int n = blockIdx.x*TPB + threadIdx.x;
  if (n < nN) disp[n] = rsqrtf((float)cnt[n] + 1.0f);   // deg includes self-loop
}

__global__ __launch_bounds__(TPB) void scan1_k(const int* __restrict__ cnt, int* __restrict__ rowptr,
                                               int* __restrict__ bsum, int nN){
  int t = threadIdx.x;
  int i = blockIdx.x*TPB + t;
  int lane = t & 63, wid = t >> 6;
  int v = (i < nN) ? cnt[i] : 0;
  int inc = wave_incl_scan(v, lane);
  __shared__ int wsum[4];
  if (lane == 63) wsum[wid] = inc;
  __syncthreads();
  int off = 0;
  #pragma unroll
  for (int w=0; w<4; ++w) if (w < wid) off += wsum[w];
  if (i < nN) rowptr[i] = inc - v + off;
  if (t == 0) bsum[blockIdx.x] = wsum[0]+wsum[1]+wsum[2]+wsum[3];
}

__global__ __launch_bounds__(TPB) void scan2_k(int* __restrict__ bsum, int nbk){
  int t = threadIdx.x;
  int lane = t & 63, wid = t >> 6;
  int v = (t < nbk) ? bsum[t] : 0;
  int inc = wave_incl_scan(v, lane);
  __shared__ int wsum[4];
  if (lane == 63) wsum[wid] = inc;
  __syncthreads();
  int off = 0;
  #pragma unroll
  for (int w=0; w<4; ++w) if (w < wid) off += wsum[w];
  __syncthreads();
  if (t < nbk) bsum[t] = inc - v + off;
}

__global__ __launch_bounds__(TPB) void scan3_k(int* __restrict__ rowptr, const int* __restrict__ bsum, int nN, int E){
  int i = blockIdx.x*TPB + threadIdx.x;
  if (i < nN) rowptr[i] += bsum[blockIdx.x];
  if (i == 0) rowptr[nN] = E;
}

__global__ __launch_bounds__(TPB) void fill_k(const int* __restrict__ srcE, const int* __restrict__ dstE,
                                              const int* __restrict__ rowptr, int* __restrict__ cursor,
                                              int* __restrict__ csr, int E){
  int e = blockIdx.x*TPB + threadIdx.x;
  if (e >= E) return;
  int d = dstE[e];
  int pos = atomicAdd(&cursor[d], 1);
  csr[rowptr[d] + pos] = srcE[e];
}

// ---------------- LayerNorm stats (wave per node) ----------------
__global__ __launch_bounds__(TPB) void ln128_k(const float* __restrict__ base, int stride,
                                               float* __restrict__ meanp, float* __restrict__ rstdp, int nN){
  int g = blockIdx.x*TPB + threadIdx.x;
  int n = g >> 6, lane = g & 63;
  if (n >= nN) return;
  const float* p = base + (size_t)n*stride;
  float v0 = p[lane], v1 = p[lane+64];
  float s  = wave_sum(v0+v1);
  float sq = wave_sum(v0*v0+v1*v1);
  float m = s * (1.f/128.f);
  float var = fmaxf(sq * (1.f/128.f) - m*m, 0.f);
  if (lane == 0){ meanp[n] = m; rstdp[n] = rsqrtf(var + 1e-5f); }
}

__global__ __launch_bounds__(TPB) void ln512_k(const float* __restrict__ x, const float* __restrict__ hbuf,
                                               float* __restrict__ meanp, float* __restrict__ rstdp, int nN){
  int g = blockIdx.x*TPB + threadIdx.x;
  int n = g >> 6, lane = g & 63;
  if (n >= nN) return;
  float s = 0.f, sq = 0.f;
  #pragma unroll
  for (int k=0;k<8;k++){
    int d = lane + k*64;
    float v = (d < 128) ? x[(size_t)n*128 + d] : hbuf[(size_t)n*384 + (d-128)];
    s += v; sq += v*v;
  }
  s = wave_sum(s); sq = wave_sum(sq);
  float m = s * (1.f/512.f);
  float var = fmaxf(sq * (1.f/512.f) - m*m, 0.f);
  if (lane == 0){ meanp[n] = m; rstdp[n] = rsqrtf(var + 1e-5f); }
}

// ---------------- weight pre-arrangement into MFMA B-fragment order ----------------
// wpre[((nt*KSTEPS + kstep)*64 + lane)*8 + b]  (bf16)
// kstep -> chunk=kstep/5, g=kstep%5 ; dloc=8*(lane>>4)+b ; d=chunk*32+dloc ; n=nt*16+(lane&15)
// g<4 -> sw[n, d*4+g] ; g==4 -> bw[n, d] ; n>=OUTW -> 0 (padding)
__global__ __launch_bounds__(TPB) void prep_wpre_k(const float* __restrict__ sw, const float* __restrict__ bw,
                                                   u16* __restrict__ wpre, int IN, int KSTEPS, int NTILES, int OUTW){
  int idx = blockIdx.x*TPB + threadIdx.x;
  if (idx >= NTILES*KSTEPS*512) return;
  int b = idx & 7, lane = (idx >> 3) & 63, rest = idx >> 9;
  int kstep = rest % KSTEPS, nt = rest / KSTEPS;
  int chunk = kstep / 5, g = kstep % 5;
  int d = chunk*32 + ((lane >> 4)*8 + b);
  int n = nt*16 + (lane & 15);
  float v = 0.f;
  if (n < OUTW) v = (g < 4) ? sw[(size_t)n*IN*4 + d*4 + g] : bw[(size_t)n*IN + d];
  wpre[idx] = f2bf(v);
}

// ---------------- fused FKAN (LN -> RBF basis + silu -> bf16 MFMA GEMM) ----------------
// SPLITN: waves partition output columns (layer, OUT=128). else waves partition rows (final, OUT=48 padded).
template<bool SPLITN, int IN, int M_REP, int N_REP>
__global__ __launch_bounds__(TPB) void fkan_mfma_k(
    const float* __restrict__ in0, int s0, int w0,
    const float* __restrict__ in1, int s1,
    const float* __restrict__ meanp, const float* __restrict__ rstdp,
    const float* __restrict__ lng, const float* __restrict__ lnb,
    const u16* __restrict__ wpre, const float* __restrict__ bias,
    float* __restrict__ outp, int ostride, int OUTW, int nN)
{
  constexpr int CH = IN / 32;            // 32 input dims per chunk -> 160 combined K = 5 MFMA ksteps
  constexpr int KSTEPS_TOT = CH * 5;
  constexpr int FLD = 168;               // row stride (bf16): 336B = 16B-aligned, 2-way-free banks
  __shared__ __align__(16) u16 Ft[64][FLD];
  __shared__ float smean[64], srstd[64];

  const int t = threadIdx.x;
  const int w = t >> 6, l = t & 63;
  const int nb0 = blockIdx.x * 64;
  if (t < 64){
    int n = nb0 + t; bool ok = n < nN;
    smean[t] = ok ? meanp[n] : 0.f;
    srstd[t] = ok ? rstdp[n] : 0.f;
  }
  const int mbase  = SPLITN ? 0 : w*16;
  const int ntbase = SPLITN ? w*N_REP : 0;
  const int clo = l & 15, kq = l >> 4;
  const float gridv[4] = {-2.f, -2.f/3.f, 2.f/3.f, 2.f};   // linspace(-2,2,4); 1/DENOM = 0.75

  f32x4 acc[M_REP][N_REP];
  #pragma unroll
  for (int m=0; m<M_REP; ++m)
    #pragma unroll
    for (int j=0; j<N_REP; ++j) acc[m][j] = (f32x4)0.f;

  for (int c=0; c<CH; ++c){
    __syncthreads();                     // Ft from previous chunk fully consumed
    // ---- build F chunk: 64 nodes x 32 dims, bf16, g-major k layout [g*32 + dloc]
    #pragma unroll
    for (int q=t; q<512; q+=TPB){
      int node = q >> 3, dg = q & 7;
      int d = c*32 + dg*4;
      int n = nb0 + node;
      float4 hv = make_float4(0.f,0.f,0.f,0.f);
      if (n < nN){
        hv = (d < w0) ? *(const float4*)(in0 + (size_t)n*s0 + d)
                      : *(const float4*)(in1 + (size_t)n*s1 + (d - w0));
      }
      float m = smean[node], r = srstd[node];
      float vv[4] = {hv.x, hv.y, hv.z, hv.w};
      u16 pk[5][4];
      #pragma unroll
      for (int u=0; u<4; ++u){
        float v = vv[u];
        float xn = (v - m)*r*lng[d+u] + lnb[d+u];
        #pragma unroll
        for (int g2=0; g2<4; ++g2){
          float z = (xn - gridv[g2]) * 0.75f;
          pk[g2][u] = f2bf(__expf(-z*z));
        }
        pk[4][u] = f2bf(v / (1.f + __expf(-v)));
      }
      #pragma unroll
      for (int g2=0; g2<5; ++g2)
        *(us4*)&Ft[node][g2*32 + dg*4] = *(const us4*)pk[g2];
    }
    __syncthreads();
    // ---- MFMA: 5 ksteps (one per g) over this chunk
    #pragma unroll
    for (int ks=0; ks<5; ++ks){
      s8v a[M_REP];
      #pragma unroll
      for (int m=0; m<M_REP; ++m)
        a[m] = *(const s8v*)&Ft[mbase + m*16 + clo][ks*32 + kq*8];
      const int kglob = c*5 + ks;
      s8v b[N_REP];
      #pragma unroll
      for (int j=0; j<N_REP; ++j)
        b[j] = *(const s8v*)(wpre + ((size_t)((ntbase + j)*KSTEPS_TOT + kglob)*64 + l)*8);
      #pragma unroll
      for (int m=0; m<M_REP; ++m)
        #pragma unroll
        for (int j=0; j<N_REP; ++j)
          acc[m][j] = __builtin_amdgcn_mfma_f32_16x16x32_bf16(a[m], b[j], acc[m][j], 0, 0, 0);
    }
  }
  // ---- epilogue: C/D layout col=lane&15, row=(lane>>4)*4+reg
  #pragma unroll
  for (int m=0; m<M_REP; ++m){
    #pragma unroll
    for (int rr=0; rr<4; ++rr){
      int node = nb0 + mbase + m*16 + kq*4 + rr;
      if (node < nN){
        #pragma unroll
        for (int j=0; j<N_REP; ++j){
          int col = (ntbase + j)*16 + clo;
          if (col < OUTW) outp[(size_t)node*ostride + col] = acc[m][j][rr] + bias[col];
        }
      }
    }
  }
}

// ---------------- GCN aggregation (gather via CSR, wave per node) ----------------
__global__ __launch_bounds__(TPB) void gcn_k(const float* __restrict__ hsrc, const int* __restrict__ rowptr,
                                             const int* __restrict__ csr, const float* __restrict__ disp,
                                             float* __restrict__ outb, int nN){
  int g = blockIdx.x*TPB + threadIdx.x;
  int n = g >> 6, lane = g & 63;
  if (n >= nN) return;
  int e0 = rowptr[n], e1 = rowptr[n+1];
  float dn = disp[n];
  float ax=0.f, ay=0.f;
  for (int e=e0; e<e1; ++e){
    int s = csr[e];
    float w = disp[s];
    float2 hv = *(const float2*)(hsrc + (size_t)s*128 + 2*lane);
    ax = fmaf(hv.x, w, ax); ay = fmaf(hv.y, w, ay);
  }
  float2 hn = *(const float2*)(hsrc + (size_t)n*128 + 2*lane);
  ax = (ax + hn.x*dn) * dn;     // self-loop term + final dis[n] factor
  ay = (ay + hn.y*dn) * dn;
  float2 r2; r2.x = ax; r2.y = ay;
  *(float2*)(outb + (size_t)n*384 + 2*lane) = r2;
}

// ---------------- BatchNorm ----------------
__global__ __launch_bounds__(TPB) void bn_stat_k(const float* __restrict__ hb, float* __restrict__ stats, int nN){
  int col  = threadIdx.x & 127;
  int half = threadIdx.x >> 7;
  float s=0.f, sq=0.f;
  for (int r = blockIdx.x*2 + half; r < nN; r += gridDim.x*2){
    float v = hb[(size_t)r*384 + col];
    s += v; sq += v*v;
  }
  __shared__ float ls[TPB], lq[TPB];
  ls[threadIdx.x]=s; lq[threadIdx.x]=sq;
  __syncthreads();
  if (half==0){
    s  = ls[threadIdx.x] + ls[threadIdx.x+128];
    sq = lq[threadIdx.x] + lq[threadIdx.x+128];
    atomicAdd(&stats[col], s);
    atomicAdd(&stats[128+col], sq);
  }
}

__global__ void bn_fin_k(const float* __restrict__ stats, const float* __restrict__ g, const float* __restrict__ b,
                         float* __restrict__ scsh, int nN){
  int c = threadIdx.x;
  float inv = 1.f/(float)nN;
  float m = stats[c]*inv;
  float var = fmaxf(stats[128+c]*inv - m*m, 0.f);
  float sc = g[c]*rsqrtf(var + 1e-5f);
  scsh[c] = sc;
  scsh[128+c] = b[c] - m*sc;
}

__global__ __launch_bounds__(TPB) void bn_apply_k(float* __restrict__ hb, const float* __restrict__ scsh, int nN){
  int idx = blockIdx.x*TPB + threadIdx.x;
  if (idx >= nN*128) return;
  int n = idx >> 7, c = idx & 127;
  float* p = hb + (size_t)n*384 + c;
  *p = fmaf(*p, scsh[c], scsh[128+c]);
}

extern "C" void kernel_launch(void* const* d_in, const int* in_sizes, int n_in,
                              void* d_out, int out_size, void* d_ws, size_t ws_size,
                              hipStream_t stream)
{
  const float* x        = (const float*)d_in[0];
  const int*   ei       = (const int*)d_in[1];
  const float* ln_g     = (const float*)d_in[2];
  const float* ln_b     = (const float*)d_in[3];
  const float* sw       = (const float*)d_in[4];
  const float* bw       = (const float*)d_in[5];
  const float* bb       = (const float*)d_in[6];
  // d_in[7] gcn_bias: per-feature constant added right before BatchNorm ->
  // exactly canceled by BN's mean subtraction (variance unchanged). Skipped.
  const float* bn_g     = (const float*)d_in[8];
  const float* bn_b     = (const float*)d_in[9];
  const float* ln_g_out = (const float*)d_in[10];
  const float* ln_b_out = (const float*)d_in[11];
  const float* sw_out   = (const float*)d_in[12];
  const float* bw_out   = (const float*)d_in[13];
  const float* bb_out   = (const float*)d_in[14];
  float* out = (float*)d_out;

  const int nN = in_sizes[0] / 128;    // 50000
  const int E  = in_sizes[1] / 2;      // 800000

  // workspace layout
  char* ws = (char*)d_ws;
  size_t off = 0;
  auto alloc = [&](size_t bytes)->char*{
    char* p = ws + off; off = (off + bytes + 255) & ~size_t(255); return p;
  };
  float* hbuf  = (float*)alloc((size_t)nN*384*4);   // [N, 3*128] BN outputs (concat tail)
  float* tmp   = (float*)alloc((size_t)nN*128*4);   // FKAN output before GCN
  float* meanp = (float*)alloc((size_t)nN*4);
  float* rstdp = (float*)alloc((size_t)nN*4);
  float* disp  = (float*)alloc((size_t)nN*4);
  float* stats = (float*)alloc(256*4);
  float* scsh  = (float*)alloc(256*4);
  u16*   wpre  = (u16*)alloc((size_t)3*80*512*2);   // max(final 3*80*512, layer 8*20*512)
  int* cnt     = (int*)alloc((size_t)nN*4);
  int* cursor  = (int*)alloc((size_t)nN*4);
  int* rowptr  = (int*)alloc((size_t)(nN+1)*4);
  int* bsum    = (int*)alloc(256*4);
  int* csr     = (int*)alloc((size_t)E*4);
  (void)ws_size; (void)n_in; (void)out_size;

  const int* srcE = ei;
  const int* dstE = ei + E;

  hipMemsetAsync(cnt, 0, (size_t)nN*4, stream);
  hipMemsetAsync(cursor, 0, (size_t)nN*4, stream);

  const int nbE = (E + TPB-1)/TPB;
  const int nbN = (nN + TPB-1)/TPB;     // 196
  count_k<<<nbE, TPB, 0, stream>>>(dstE, cnt, E);
  dis_k<<<nbN, TPB, 0, stream>>>(cnt, disp, nN);
  scan1_k<<<nbN, TPB, 0, stream>>>(cnt, rowptr, bsum, nN);
  scan2_k<<<1, TPB, 0, stream>>>(bsum, nbN);
  scan3_k<<<nbN, TPB, 0, stream>>>(rowptr, bsum, nN, E);
  fill_k<<<nbE, TPB, 0, stream>>>(srcE, dstE, rowptr, cursor, csr, E);

  const int nbW = (nN*64 + TPB-1)/TPB;  // wave-per-node kernels
  const int nbF = (nN + 63)/64;         // fkan blocks (64 nodes each)

  for (int i=0; i<3; ++i){
    const float* inbase = (i==0) ? x : (hbuf + (size_t)(i-1)*128);
    int instride = (i==0) ? 128 : 384;
    ln128_k<<<nbW, TPB, 0, stream>>>(inbase, instride, meanp, rstdp, nN);
    prep_wpre_k<<<(8*20*512 + TPB-1)/TPB, TPB, 0, stream>>>(
        sw + (size_t)i*128*512, bw + (size_t)i*128*128, wpre, 128, 20, 8, 128);
    fkan_mfma_k<true,128,4,2><<<nbF, TPB, 0, stream>>>(
        inbase, instride, 128, (const float*)nullptr, 0,
        meanp, rstdp, ln_g + (size_t)i*128, ln_b + (size_t)i*128,
        wpre, bb + (size_t)i*128, tmp, 128, 128, nN);
    gcn_k<<<nbW, TPB, 0, stream>>>(tmp, rowptr, csr, disp, hbuf + (size_t)i*128, nN);
    hipMemsetAsync(stats, 0, 256*4, stream);
    bn_stat_k<<<256, TPB, 0, stream>>>(hbuf + (size_t)i*128, stats, nN);
    bn_fin_k<<<1, 128, 0, stream>>>(stats, bn_g + (size_t)i*128, bn_b + (size_t)i*128, scsh, nN);
    bn_apply_k<<<(nN*128 + TPB-1)/TPB, TPB, 0, stream>>>(hbuf + (size_t)i*128, scsh, nN);
  }

  // final FKAN on concat [x | hbuf]  (512 -> 40, padded to 48)
  ln512_k<<<nbW, TPB, 0, stream>>>(x, hbuf, meanp, rstdp, nN);
  prep_wpre_k<<<(3*80*512 + TPB-1)/TPB, TPB, 0, stream>>>(
      sw_out, bw_out, wpre, 512, 80, 3, 40);
  fkan_mfma_k<false,512,1,3><<<nbF, TPB, 0, stream>>>(
      x, 128, 128, hbuf, 384,
      meanp, rstdp, ln_g_out, ln_b_out,
      wpre, bb_out, out, 40, 40, nN);
}

// Round 3
// 558.792 us; speedup vs baseline: 2.1545x; 1.2524x over previous
//
#include <hip/hip_runtime.h>

#define TPB 256

typedef __attribute__((ext_vector_type(8))) short s8v;     // 8 bf16 (4 VGPR) MFMA A/B frag
typedef __attribute__((ext_vector_type(4))) float f32x4;   // MFMA C/D frag
typedef __attribute__((ext_vector_type(4))) unsigned short us4;
typedef unsigned short u16;

__device__ __forceinline__ u16 f2bf(float f){
  unsigned u = __float_as_uint(f);
  u += 0x7fff + ((u >> 16) & 1);       // round-to-nearest-even
  return (u16)(u >> 16);
}

__device__ __forceinline__ float wave_sum(float v){
  #pragma unroll
  for (int off=32; off>0; off>>=1) v += __shfl_xor(v, off, 64);
  return v;
}

__device__ __forceinline__ int wave_incl_scan(int v, int lane){
  #pragma unroll
  for (int off=1; off<64; off<<=1){
    int u = __shfl_up(v, off, 64);
    if (lane >= off) v += u;
  }
  return v;
}

// ---------------- CSR build ----------------
__global__ __launch_bounds__(TPB) void count_k(const int* __restrict__ dstE, int* __restrict__ cnt, int E){
  int e = blockIdx.x*TPB + threadIdx.x;
  if (e < E) atomicAdd(&cnt[dstE[e]], 1);
}

__global__ __launch_bounds__(TPB) void dis_k(const int* __restrict__ cnt, float* __restrict__ disp, int nN){
  int n = blockIdx.x*TPB + threadIdx.x;
  if (n < nN) disp[n] = rsqrtf((float)cnt[n] + 1.0f);   // deg includes self-loop
}

__global__ __launch_bounds__(TPB) void scan1_k(const int* __restrict__ cnt, int* __restrict__ rowptr,
                                               int* __restrict__ bsum, int nN){
  int t = threadIdx.x;
  int i = blockIdx.x*TPB + t;
  int lane = t & 63, wid = t >> 6;
  int v = (i < nN) ? cnt[i] : 0;
  int inc = wave_incl_scan(v, lane);
  __shared__ int wsum[4];
  if (lane == 63) wsum[wid] = inc;
  __syncthreads();
  int off = 0;
  #pragma unroll
  for (int w=0; w<4; ++w) if (w < wid) off += wsum[w];
  if (i < nN) rowptr[i] = inc - v + off;
  if (t == 0) bsum[blockIdx.x] = wsum[0]+wsum[1]+wsum[2]+wsum[3];
}

__global__ __launch_bounds__(TPB) void scan2_k(int* __restrict__ bsum, int nbk){
  int t = threadIdx.x;
  int lane = t & 63, wid = t >> 6;
  int v = (t < nbk) ? bsum[t] : 0;
  int inc = wave_incl_scan(v, lane);
  __shared__ int wsum[4];
  if (lane == 63) wsum[wid] = inc;
  __syncthreads();
  int off = 0;
  #pragma unroll
  for (int w=0; w<4; ++w) if (w < wid) off += wsum[w];
  __syncthreads();
  if (t < nbk) bsum[t] = inc - v + off;
}

__global__ __launch_bounds__(TPB) void scan3_k(int* __restrict__ rowptr, const int* __restrict__ bsum, int nN, int E){
  int i = blockIdx.x*TPB + threadIdx.x;
  if (i < nN) rowptr[i] += bsum[blockIdx.x];
  if (i == 0) rowptr[nN] = E;
}

__global__ __launch_bounds__(TPB) void fill_k(const int* __restrict__ srcE, const int* __restrict__ dstE,
                                              const int* __restrict__ rowptr, int* __restrict__ cursor,
                                              int* __restrict__ csr, int E){
  int e = blockIdx.x*TPB + threadIdx.x;
  if (e >= E) return;
  int d = dstE[e];
  int pos = atomicAdd(&cursor[d], 1);
  csr[rowptr[d] + pos] = srcE[e];
}

// ---------------- LayerNorm stats (wave per node) ----------------
__global__ __launch_bounds__(TPB) void ln128_k(const float* __restrict__ base, int stride,
                                               float* __restrict__ meanp, float* __restrict__ rstdp, int nN){
  int g = blockIdx.x*TPB + threadIdx.x;
  int n = g >> 6, lane = g & 63;
  if (n >= nN) return;
  const float* p = base + (size_t)n*stride;
  float v0 = p[lane], v1 = p[lane+64];
  float s  = wave_sum(v0+v1);
  float sq = wave_sum(v0*v0+v1*v1);
  float m = s * (1.f/128.f);
  float var = fmaxf(sq * (1.f/128.f) - m*m, 0.f);
  if (lane == 0){ meanp[n] = m; rstdp[n] = rsqrtf(var + 1e-5f); }
}

__global__ __launch_bounds__(TPB) void ln512_k(const float* __restrict__ x, const float* __restrict__ hbuf,
                                               float* __restrict__ meanp, float* __restrict__ rstdp, int nN){
  int g = blockIdx.x*TPB + threadIdx.x;
  int n = g >> 6, lane = g & 63;
  if (n >= nN) return;
  float s = 0.f, sq = 0.f;
  #pragma unroll
  for (int k=0;k<8;k++){
    int d = lane + k*64;
    float v = (d < 128) ? x[(size_t)n*128 + d] : hbuf[(size_t)n*384 + (d-128)];
    s += v; sq += v*v;
  }
  s = wave_sum(s); sq = wave_sum(sq);
  float m = s * (1.f/512.f);
  float var = fmaxf(sq * (1.f/512.f) - m*m, 0.f);
  if (lane == 0){ meanp[n] = m; rstdp[n] = rsqrtf(var + 1e-5f); }
}

// ---------------- weight pre-arrangement into MFMA B-fragment order ----------------
__global__ __launch_bounds__(TPB) void prep_wpre_k(const float* __restrict__ sw, const float* __restrict__ bw,
                                                   u16* __restrict__ wpre, int IN, int KSTEPS, int NTILES, int OUTW){
  int idx = blockIdx.x*TPB + threadIdx.x;
  if (idx >= NTILES*KSTEPS*512) return;
  int b = idx & 7, lane = (idx >> 3) & 63, rest = idx >> 9;
  int kstep = rest % KSTEPS, nt = rest / KSTEPS;
  int chunk = kstep / 5, g = kstep % 5;
  int d = chunk*32 + ((lane >> 4)*8 + b);
  int n = nt*16 + (lane & 15);
  float v = 0.f;
  if (n < OUTW) v = (g < 4) ? sw[(size_t)n*IN*4 + d*4 + g] : bw[(size_t)n*IN + d];
  wpre[idx] = f2bf(v);
}

// ---------------- fused FKAN (LN -> RBF basis + silu -> bf16 MFMA GEMM) ----------------
// SPLITN: waves partition output columns (layer). SCALED: write bf16 hs = val*disp[node].
template<bool SPLITN, bool SCALED, int IN, int M_REP, int N_REP>
__global__ __launch_bounds__(TPB) void fkan_mfma_k(
    const float* __restrict__ in0, int s0, int w0,
    const float* __restrict__ in1, int s1,
    const float* __restrict__ meanp, const float* __restrict__ rstdp,
    const float* __restrict__ lng, const float* __restrict__ lnb,
    const u16* __restrict__ wpre, const float* __restrict__ bias,
    const float* __restrict__ dispp,
    float* __restrict__ outp, u16* __restrict__ outbf, int ostride, int OUTW, int nN)
{
  constexpr int CH = IN / 32;
  constexpr int KSTEPS_TOT = CH * 5;
  constexpr int FLD = 168;               // row stride (bf16): 336B = 16B-aligned, 2-way-free banks
  __shared__ __align__(16) u16 Ft[64][FLD];
  __shared__ float smean[64], srstd[64];

  const int t = threadIdx.x;
  const int w = t >> 6, l = t & 63;
  const int nb0 = blockIdx.x * 64;
  if (t < 64){
    int n = nb0 + t; bool ok = n < nN;
    smean[t] = ok ? meanp[n] : 0.f;
    srstd[t] = ok ? rstdp[n] : 0.f;
  }
  const int mbase  = SPLITN ? 0 : w*16;
  const int ntbase = SPLITN ? w*N_REP : 0;
  const int clo = l & 15, kq = l >> 4;
  const float gridv[4] = {-2.f, -2.f/3.f, 2.f/3.f, 2.f};   // linspace(-2,2,4); 1/DENOM = 0.75

  f32x4 acc[M_REP][N_REP];
  #pragma unroll
  for (int m=0; m<M_REP; ++m)
    #pragma unroll
    for (int j=0; j<N_REP; ++j) acc[m][j] = (f32x4)0.f;

  for (int c=0; c<CH; ++c){
    __syncthreads();
    #pragma unroll
    for (int q=t; q<512; q+=TPB){
      int node = q >> 3, dg = q & 7;
      int d = c*32 + dg*4;
      int n = nb0 + node;
      float4 hv = make_float4(0.f,0.f,0.f,0.f);
      if (n < nN){
        hv = (d < w0) ? *(const float4*)(in0 + (size_t)n*s0 + d)
                      : *(const float4*)(in1 + (size_t)n*s1 + (d - w0));
      }
      float m = smean[node], r = srstd[node];
      float vv[4] = {hv.x, hv.y, hv.z, hv.w};
      u16 pk[5][4];
      #pragma unroll
      for (int u=0; u<4; ++u){
        float v = vv[u];
        float xn = (v - m)*r*lng[d+u] + lnb[d+u];
        #pragma unroll
        for (int g2=0; g2<4; ++g2){
          float z = (xn - gridv[g2]) * 0.75f;
          pk[g2][u] = f2bf(__expf(-z*z));
        }
        pk[4][u] = f2bf(v / (1.f + __expf(-v)));
      }
      #pragma unroll
      for (int g2=0; g2<5; ++g2)
        *(us4*)&Ft[node][g2*32 + dg*4] = *(const us4*)pk[g2];
    }
    __syncthreads();
    #pragma unroll
    for (int ks=0; ks<5; ++ks){
      s8v a[M_REP];
      #pragma unroll
      for (int m=0; m<M_REP; ++m)
        a[m] = *(const s8v*)&Ft[mbase + m*16 + clo][ks*32 + kq*8];
      const int kglob = c*5 + ks;
      s8v b[N_REP];
      #pragma unroll
      for (int j=0; j<N_REP; ++j)
        b[j] = *(const s8v*)(wpre + ((size_t)((ntbase + j)*KSTEPS_TOT + kglob)*64 + l)*8);
      #pragma unroll
      for (int m=0; m<M_REP; ++m)
        #pragma unroll
        for (int j=0; j<N_REP; ++j)
          acc[m][j] = __builtin_amdgcn_mfma_f32_16x16x32_bf16(a[m], b[j], acc[m][j], 0, 0, 0);
    }
  }
  // ---- epilogue: C/D layout col=lane&15, row=(lane>>4)*4+reg
  #pragma unroll
  for (int m=0; m<M_REP; ++m){
    #pragma unroll
    for (int rr=0; rr<4; ++rr){
      int node = nb0 + mbase + m*16 + kq*4 + rr;
      if (node < nN){
        float dsc = SCALED ? dispp[node] : 1.f;
        #pragma unroll
        for (int j=0; j<N_REP; ++j){
          int col = (ntbase + j)*16 + clo;
          if (col < OUTW){
            float val = acc[m][j][rr] + bias[col];
            if (SCALED) outbf[(size_t)node*OUTW + col] = f2bf(val * dsc);
            else        outp[(size_t)node*ostride + col] = val;
          }
        }
      }
    }
  }
}

// ---------------- GCN aggregation: sum of pre-scaled bf16 rows, x disp[n] ----------------
__device__ __forceinline__ void acc_bf2(unsigned u, float& ax, float& ay){
  ax += __uint_as_float(u << 16);
  ay += __uint_as_float(u & 0xffff0000u);
}

__global__ __launch_bounds__(TPB) void gcn_k(const u16* __restrict__ hs, const int* __restrict__ rowptr,
                                             const int* __restrict__ csr, const float* __restrict__ disp,
                                             float* __restrict__ outb, int nN){
  int g = blockIdx.x*TPB + threadIdx.x;
  int n = g >> 6, lane = g & 63;
  if (n >= nN) return;
  const unsigned* H = (const unsigned*)hs;    // 64 dwords per row (128 bf16)
  int e0 = rowptr[n], e1 = rowptr[n+1];
  float ax=0.f, ay=0.f;
  int e = e0;
  for (; e + 4 <= e1; e += 4){
    int s0 = csr[e], s1 = csr[e+1], s2 = csr[e+2], s3 = csr[e+3];
    unsigned u0 = H[(size_t)s0*64 + lane];
    unsigned u1 = H[(size_t)s1*64 + lane];
    unsigned u2 = H[(size_t)s2*64 + lane];
    unsigned u3 = H[(size_t)s3*64 + lane];
    acc_bf2(u0, ax, ay); acc_bf2(u1, ax, ay);
    acc_bf2(u2, ax, ay); acc_bf2(u3, ax, ay);
  }
  for (; e < e1; ++e){
    unsigned u = H[(size_t)csr[e]*64 + lane];
    acc_bf2(u, ax, ay);
  }
  unsigned un = H[(size_t)n*64 + lane];        // self-loop (hs already has dis[n] factor)
  acc_bf2(un, ax, ay);
  float dn = disp[n];
  float2 r2; r2.x = ax*dn; r2.y = ay*dn;
  *(float2*)(outb + (size_t)n*384 + 2*lane) = r2;
}

// ---------------- BatchNorm ----------------
__global__ __launch_bounds__(TPB) void bn_stat_k(const float* __restrict__ hb, float* __restrict__ stats, int nN){
  int col  = threadIdx.x & 127;
  int half = threadIdx.x >> 7;
  float s=0.f, sq=0.f;
  for (int r = blockIdx.x*2 + half; r < nN; r += gridDim.x*2){
    float v = hb[(size_t)r*384 + col];
    s += v; sq += v*v;
  }
  __shared__ float ls[TPB], lq[TPB];
  ls[threadIdx.x]=s; lq[threadIdx.x]=sq;
  __syncthreads();
  if (half==0){
    s  = ls[threadIdx.x] + ls[threadIdx.x+128];
    sq = lq[threadIdx.x] + lq[threadIdx.x+128];
    atomicAdd(&stats[col], s);
    atomicAdd(&stats[128+col], sq);
  }
}

__global__ void bn_fin_k(const float* __restrict__ stats, const float* __restrict__ g, const float* __restrict__ b,
                         float* __restrict__ scsh, int nN){
  int c = threadIdx.x;
  float inv = 1.f/(float)nN;
  float m = stats[c]*inv;
  float var = fmaxf(stats[128+c]*inv - m*m, 0.f);
  float sc = g[c]*rsqrtf(var + 1e-5f);
  scsh[c] = sc;
  scsh[128+c] = b[c] - m*sc;
}

__global__ __launch_bounds__(TPB) void bn_apply_k(float* __restrict__ hb, const float* __restrict__ scsh, int nN){
  int idx = blockIdx.x*TPB + threadIdx.x;
  if (idx >= nN*128) return;
  int n = idx >> 7, c = idx & 127;
  float* p = hb + (size_t)n*384 + c;
  *p = fmaf(*p, scsh[c], scsh[128+c]);
}

extern "C" void kernel_launch(void* const* d_in, const int* in_sizes, int n_in,
                              void* d_out, int out_size, void* d_ws, size_t ws_size,
                              hipStream_t stream)
{
  const float* x        = (const float*)d_in[0];
  const int*   ei       = (const int*)d_in[1];
  const float* ln_g     = (const float*)d_in[2];
  const float* ln_b     = (const float*)d_in[3];
  const float* sw       = (const float*)d_in[4];
  const float* bw       = (const float*)d_in[5];
  const float* bb       = (const float*)d_in[6];
  // d_in[7] gcn_bias: canceled exactly by BatchNorm mean subtraction. Skipped.
  const float* bn_g     = (const float*)d_in[8];
  const float* bn_b     = (const float*)d_in[9];
  const float* ln_g_out = (const float*)d_in[10];
  const float* ln_b_out = (const float*)d_in[11];
  const float* sw_out   = (const float*)d_in[12];
  const float* bw_out   = (const float*)d_in[13];
  const float* bb_out   = (const float*)d_in[14];
  float* out = (float*)d_out;

  const int nN = in_sizes[0] / 128;    // 50000
  const int E  = in_sizes[1] / 2;      // 800000

  char* ws = (char*)d_ws;
  size_t off = 0;
  auto alloc = [&](size_t bytes)->char*{
    char* p = ws + off; off = (off + bytes + 255) & ~size_t(255); return p;
  };
  float* hbuf  = (float*)alloc((size_t)nN*384*4);   // [N, 3*128] BN outputs (concat tail)
  u16*   hs    = (u16*)alloc((size_t)nN*128*2);     // pre-scaled bf16 FKAN output (GCN input)
  float* meanp = (float*)alloc((size_t)nN*4);
  float* rstdp = (float*)alloc((size_t)nN*4);
  float* disp  = (float*)alloc((size_t)nN*4);
  float* stats = (float*)alloc(256*4);
  float* scsh  = (float*)alloc(256*4);
  u16*   wpre  = (u16*)alloc((size_t)3*80*512*2);
  int* cnt     = (int*)alloc((size_t)nN*4);
  int* cursor  = (int*)alloc((size_t)nN*4);
  int* rowptr  = (int*)alloc((size_t)(nN+1)*4);
  int* bsum    = (int*)alloc(256*4);
  int* csr     = (int*)alloc((size_t)E*4);
  (void)ws_size; (void)n_in; (void)out_size;

  const int* srcE = ei;
  const int* dstE = ei + E;

  hipMemsetAsync(cnt, 0, (size_t)nN*4, stream);
  hipMemsetAsync(cursor, 0, (size_t)nN*4, stream);

  const int nbE = (E + TPB-1)/TPB;
  const int nbN = (nN + TPB-1)/TPB;
  count_k<<<nbE, TPB, 0, stream>>>(dstE, cnt, E);
  dis_k<<<nbN, TPB, 0, stream>>>(cnt, disp, nN);
  scan1_k<<<nbN, TPB, 0, stream>>>(cnt, rowptr, bsum, nN);
  scan2_k<<<1, TPB, 0, stream>>>(bsum, nbN);
  scan3_k<<<nbN, TPB, 0, stream>>>(rowptr, bsum, nN, E);
  fill_k<<<nbE, TPB, 0, stream>>>(srcE, dstE, rowptr, cursor, csr, E);

  const int nbW = (nN*64 + TPB-1)/TPB;  // wave-per-node kernels
  const int nbF = (nN + 63)/64;         // fkan blocks (64 nodes each)

  for (int i=0; i<3; ++i){
    const float* inbase = (i==0) ? x : (hbuf + (size_t)(i-1)*128);
    int instride = (i==0) ? 128 : 384;
    ln128_k<<<nbW, TPB, 0, stream>>>(inbase, instride, meanp, rstdp, nN);
    prep_wpre_k<<<(8*20*512 + TPB-1)/TPB, TPB, 0, stream>>>(
        sw + (size_t)i*128*512, bw + (size_t)i*128*128, wpre, 128, 20, 8, 128);
    fkan_mfma_k<true,true,128,4,2><<<nbF, TPB, 0, stream>>>(
        inbase, instride, 128, (const float*)nullptr, 0,
        meanp, rstdp, ln_g + (size_t)i*128, ln_b + (size_t)i*128,
        wpre, bb + (size_t)i*128, disp, (float*)nullptr, hs, 128, 128, nN);
    gcn_k<<<nbW, TPB, 0, stream>>>(hs, rowptr, csr, disp, hbuf + (size_t)i*128, nN);
    hipMemsetAsync(stats, 0, 256*4, stream);
    bn_stat_k<<<256, TPB, 0, stream>>>(hbuf + (size_t)i*128, stats, nN);
    bn_fin_k<<<1, 128, 0, stream>>>(stats, bn_g + (size_t)i*128, bn_b + (size_t)i*128, scsh, nN);
    bn_apply_k<<<(nN*128 + TPB-1)/TPB, TPB, 0, stream>>>(hbuf + (size_t)i*128, scsh, nN);
  }

  // final FKAN on concat [x | hbuf]  (512 -> 40, padded to 48)
  ln512_k<<<nbW, TPB, 0, stream>>>(x, hbuf, meanp, rstdp, nN);
  prep_wpre_k<<<(3*80*512 + TPB-1)/TPB, TPB, 0, stream>>>(
      sw_out, bw_out, wpre, 512, 80, 3, 40);
  fkan_mfma_k<false,false,512,1,3><<<nbF, TPB, 0, stream>>>(
      x, 128, 128, hbuf, 384,
      meanp, rstdp, ln_g_out, ln_b_out,
      wpre, bb_out, (const float*)nullptr, out, (u16*)nullptr, 40, 40, nN);
}

// Round 5
// 554.925 us; speedup vs baseline: 2.1695x; 1.0070x over previous
//
#include <hip/hip_runtime.h>

#define TPB 256

typedef __attribute__((ext_vector_type(8))) short s8v;     // 8 bf16 (4 VGPR) MFMA A/B frag
typedef __attribute__((ext_vector_type(4))) float f32x4;   // MFMA C/D frag
typedef unsigned short u16;

__device__ __forceinline__ u16 f2bf(float f){
  unsigned u = __float_as_uint(f);
  u += 0x7fff + ((u >> 16) & 1);       // round-to-nearest-even
  return (u16)(u >> 16);
}

__device__ __forceinline__ unsigned pack_bf2(float lo, float hi){
  return (unsigned)f2bf(lo) | ((unsigned)f2bf(hi) << 16);
}

__device__ __forceinline__ float wave_sum(float v){
  #pragma unroll
  for (int off=32; off>0; off>>=1) v += __shfl_xor(v, off, 64);
  return v;
}

__device__ __forceinline__ int wave_incl_scan(int v, int lane){
  #pragma unroll
  for (int off=1; off<64; off<<=1){
    int u = __shfl_up(v, off, 64);
    if (lane >= off) v += u;
  }
  return v;
}

// ---------------- CSR build ----------------
__global__ __launch_bounds__(TPB) void count_k(const int* __restrict__ dstE, int* __restrict__ cnt, int E){
  int e = blockIdx.x*TPB + threadIdx.x;
  if (e < E) atomicAdd(&cnt[dstE[e]], 1);
}

__global__ __launch_bounds__(TPB) void dis_k(const int* __restrict__ cnt, float* __restrict__ disp, int nN){
  int n = blockIdx.x*TPB + threadIdx.x;
  if (n < nN) disp[n] = rsqrtf((float)cnt[n] + 1.0f);   // deg includes self-loop
}

__global__ __launch_bounds__(TPB) void scan1_k(const int* __restrict__ cnt, int* __restrict__ rowptr,
                                               int* __restrict__ bsum, int nN){
  int t = threadIdx.x;
  int i = blockIdx.x*TPB + t;
  int lane = t & 63, wid = t >> 6;
  int v = (i < nN) ? cnt[i] : 0;
  int inc = wave_incl_scan(v, lane);
  __shared__ int wsum[4];
  if (lane == 63) wsum[wid] = inc;
  __syncthreads();
  int off = 0;
  #pragma unroll
  for (int w=0; w<4; ++w) if (w < wid) off += wsum[w];
  if (i < nN) rowptr[i] = inc - v + off;
  if (t == 0) bsum[blockIdx.x] = wsum[0]+wsum[1]+wsum[2]+wsum[3];
}

__global__ __launch_bounds__(TPB) void scan2_k(int* __restrict__ bsum, int nbk){
  int t = threadIdx.x;
  int lane = t & 63, wid = t >> 6;
  int v = (t < nbk) ? bsum[t] : 0;
  int inc = wave_incl_scan(v, lane);
  __shared__ int wsum[4];
  if (lane == 63) wsum[wid] = inc;
  __syncthreads();
  int off = 0;
  #pragma unroll
  for (int w=0; w<4; ++w) if (w < wid) off += wsum[w];
  __syncthreads();
  if (t < nbk) bsum[t] = inc - v + off;
}

__global__ __launch_bounds__(TPB) void scan3_k(int* __restrict__ rowptr, const int* __restrict__ bsum, int nN, int E){
  int i = blockIdx.x*TPB + threadIdx.x;
  if (i < nN) rowptr[i] += bsum[blockIdx.x];
  if (i == 0) rowptr[nN] = E;
}

__global__ __launch_bounds__(TPB) void fill_k(const int* __restrict__ srcE, const int* __restrict__ dstE,
                                              const int* __restrict__ rowptr, int* __restrict__ cursor,
                                              int* __restrict__ csr, int E){
  int e = blockIdx.x*TPB + threadIdx.x;
  if (e >= E) return;
  int d = dstE[e];
  int pos = atomicAdd(&cursor[d], 1);
  csr[rowptr[d] + pos] = srcE[e];
}

// ---------------- LayerNorm stats for final concat row (wave per node) ----------------
__global__ __launch_bounds__(TPB) void ln512_k(const float* __restrict__ x, const float* __restrict__ hbuf,
                                               float* __restrict__ meanp, float* __restrict__ rstdp, int nN){
  int g = blockIdx.x*TPB + threadIdx.x;
  int n = g >> 6, lane = g & 63;
  if (n >= nN) return;
  float s = 0.f, sq = 0.f;
  #pragma unroll
  for (int k=0;k<8;k++){
    int d = lane + k*64;
    float v = (d < 128) ? x[(size_t)n*128 + d] : hbuf[(size_t)n*384 + (d-128)];
    s += v; sq += v*v;
  }
  s = wave_sum(s); sq = wave_sum(sq);
  float m = s * (1.f/512.f);
  float var = fmaxf(sq * (1.f/512.f) - m*m, 0.f);
  if (lane == 0){ meanp[n] = m; rstdp[n] = rsqrtf(var + 1e-5f); }
}

// ---------------- weight pre-arrangement into MFMA B-fragment order ----------------
__global__ __launch_bounds__(TPB) void prep_wpre_k(const float* __restrict__ sw, const float* __restrict__ bw,
                                                   u16* __restrict__ wpre, int IN, int KSTEPS, int NTILES, int OUTW){
  int idx = blockIdx.x*TPB + threadIdx.x;
  if (idx >= NTILES*KSTEPS*512) return;
  int b = idx & 7, lane = (idx >> 3) & 63, rest = idx >> 9;
  int kstep = rest % KSTEPS, nt = rest / KSTEPS;
  int chunk = kstep / 5, g = kstep % 5;
  int d = chunk*32 + ((lane >> 4)*8 + b);
  int n = nt*16 + (lane & 15);
  float v = 0.f;
  if (n < OUTW) v = (g < 4) ? sw[(size_t)n*IN*4 + d*4 + g] : bw[(size_t)n*IN + d];
  wpre[idx] = f2bf(v);
}

// ---------------- A-fragment build: 8 dims -> 5 bf16x8 frags (4 basis + silu) ----------------
__device__ __forceinline__ void build_frags(const float* __restrict__ h8, float mean, float rstd,
                                            const float* __restrict__ lngv, const float* __restrict__ lnbv,
                                            s8v* __restrict__ a){
  float bas[5][8];
  #pragma unroll
  for (int u=0; u<8; ++u){
    float v = h8[u];
    float xn = (v - mean)*rstd*lngv[u] + lnbv[u];
    float y = 0.75f*xn;                               // (xn - g)/DENOM, DENOM = 4/3
    float z0 = y+1.5f, z1 = y+0.5f, z2 = y-0.5f, z3 = y-1.5f;
    bas[0][u] = __expf(-z0*z0);
    bas[1][u] = __expf(-z1*z1);
    bas[2][u] = __expf(-z2*z2);
    bas[3][u] = __expf(-z3*z3);
    bas[4][u] = v * __builtin_amdgcn_rcpf(1.f + __expf(-v));   // silu
  }
  #pragma unroll
  for (int g=0; g<5; ++g){
    #pragma unroll
    for (int j=0; j<4; ++j)
      ((unsigned*)&a[g])[j] = pack_bf2(bas[g][2*j], bas[g][2*j+1]);
  }
}

// ---------------- fused FKAN layer: fused LN + register A-frags, no LDS, no barriers ----------
// wave = 16 nodes x 128 outs; lane (kq=l>>4, clo=l&15) holds node clo, dims kq*8.. per chunk.
__global__ __launch_bounds__(TPB) void fkan_layer_k(
    const float* __restrict__ in, int istride,
    const float* __restrict__ lng, const float* __restrict__ lnb,
    const u16* __restrict__ wpre, const float* __restrict__ bias,
    const float* __restrict__ disp, u16* __restrict__ hs, int nN)
{
  const int t = threadIdx.x;
  const int wv = blockIdx.x*(TPB/64) + (t >> 6);
  const int nwaves = (nN + 15) >> 4;
  if (wv >= nwaves) return;
  const int l = t & 63, clo = l & 15, kq = l >> 4;
  const int node = wv*16 + clo;
  const int nc = node < nN ? node : nN-1;
  const float* hrow = in + (size_t)nc*istride;

  float h[4][8];
  #pragma unroll
  for (int c=0; c<4; ++c){
    *(float4*)&h[c][0] = *(const float4*)(hrow + c*32 + kq*8);
    *(float4*)&h[c][4] = *(const float4*)(hrow + c*32 + kq*8 + 4);
  }
  // fused LayerNorm stats: lane partial over its 32 dims, combine across the 4 kq groups
  float s = 0.f, sq = 0.f;
  #pragma unroll
  for (int c=0; c<4; ++c)
    #pragma unroll
    for (int u=0; u<8; ++u){ float v = h[c][u]; s += v; sq += v*v; }
  s  += __shfl_xor(s, 16, 64);  s  += __shfl_xor(s, 32, 64);
  sq += __shfl_xor(sq, 16, 64); sq += __shfl_xor(sq, 32, 64);
  float mean = s * (1.f/128.f);
  float var  = fmaxf(sq * (1.f/128.f) - mean*mean, 0.f);
  float rstd = rsqrtf(var + 1e-5f);

  f32x4 acc[8];
  #pragma unroll
  for (int j=0; j<8; ++j) acc[j] = (f32x4)0.f;

  for (int c=0; c<4; ++c){
    float lngv[8], lnbv[8];
    *(float4*)&lngv[0] = *(const float4*)(lng + c*32 + kq*8);
    *(float4*)&lngv[4] = *(const float4*)(lng + c*32 + kq*8 + 4);
    *(float4*)&lnbv[0] = *(const float4*)(lnb + c*32 + kq*8);
    *(float4*)&lnbv[4] = *(const float4*)(lnb + c*32 + kq*8 + 4);
    s8v a[5];
    build_frags(h[c], mean, rstd, lngv, lnbv, a);
    #pragma unroll
    for (int ks=0; ks<5; ++ks){
      const int kglob = c*5 + ks;
      #pragma unroll
      for (int j=0; j<8; ++j){
        s8v b = *(const s8v*)(wpre + ((size_t)(j*20 + kglob)*64 + l)*8);
        acc[j] = __builtin_amdgcn_mfma_f32_16x16x32_bf16(a[ks], b, acc[j], 0, 0, 0);
      }
    }
  }
  // epilogue: C/D col = clo, row = kq*4+rr ; hs = (acc+bias)*disp[node], bf16
  float bv[8];
  #pragma unroll
  for (int j=0; j<8; ++j) bv[j] = bias[j*16 + clo];
  #pragma unroll
  for (int rr=0; rr<4; ++rr){
    int nw = wv*16 + kq*4 + rr;
    if (nw < nN){
      float dsc = disp[nw];
      #pragma unroll
      for (int j=0; j<8; ++j)
        hs[(size_t)nw*128 + j*16 + clo] = f2bf((acc[j][rr] + bv[j]) * dsc);
    }
  }
}

// ---------------- final FKAN on concat row (IN=512 -> 40 cols, padded 48) ----------------
// wave = 32 nodes (M_REP=2) x 48 outs (N_REP=3); LN stats from ln512_k.
__global__ __launch_bounds__(TPB) void fkan_out_k(
    const float* __restrict__ x, const float* __restrict__ hbuf,
    const float* __restrict__ meanp, const float* __restrict__ rstdp,
    const float* __restrict__ lng, const float* __restrict__ lnb,
    const u16* __restrict__ wpre, const float* __restrict__ bias,
    float* __restrict__ out, int nN)
{
  const int t = threadIdx.x;
  const int wv = blockIdx.x*(TPB/64) + (t >> 6);
  const int nwaves = (nN + 31) >> 5;
  if (wv >= nwaves) return;
  const int l = t & 63, clo = l & 15, kq = l >> 4;
  int nc0 = wv*32 + clo;      nc0 = nc0 < nN ? nc0 : nN-1;
  int nc1 = wv*32 + 16 + clo; nc1 = nc1 < nN ? nc1 : nN-1;
  const float mean0 = meanp[nc0], rstd0 = rstdp[nc0];
  const float mean1 = meanp[nc1], rstd1 = rstdp[nc1];

  f32x4 acc[2][3];
  #pragma unroll
  for (int m=0; m<2; ++m)
    #pragma unroll
    for (int j=0; j<3; ++j) acc[m][j] = (f32x4)0.f;

  for (int c=0; c<16; ++c){
    const int d0 = c*32 + kq*8;
    float lngv[8], lnbv[8];
    *(float4*)&lngv[0] = *(const float4*)(lng + d0);
    *(float4*)&lngv[4] = *(const float4*)(lng + d0 + 4);
    *(float4*)&lnbv[0] = *(const float4*)(lnb + d0);
    *(float4*)&lnbv[4] = *(const float4*)(lnb + d0 + 4);
    const float* s0 = (d0 < 128) ? (x + (size_t)nc0*128 + d0) : (hbuf + (size_t)nc0*384 + (d0-128));
    const float* s1 = (d0 < 128) ? (x + (size_t)nc1*128 + d0) : (hbuf + (size_t)nc1*384 + (d0-128));
    float h0[8], h1[8];
    *(float4*)&h0[0] = *(const float4*)(s0);  *(float4*)&h0[4] = *(const float4*)(s0+4);
    *(float4*)&h1[0] = *(const float4*)(s1);  *(float4*)&h1[4] = *(const float4*)(s1+4);
    s8v a0[5], a1[5];
    build_frags(h0, mean0, rstd0, lngv, lnbv, a0);
    build_frags(h1, mean1, rstd1, lngv, lnbv, a1);
    #pragma unroll
    for (int ks=0; ks<5; ++ks){
      const int kglob = c*5 + ks;
      #pragma unroll
      for (int j=0; j<3; ++j){
        s8v b = *(const s8v*)(wpre + ((size_t)(j*80 + kglob)*64 + l)*8);
        acc[0][j] = __builtin_amdgcn_mfma_f32_16x16x32_bf16(a0[ks], b, acc[0][j], 0, 0, 0);
        acc[1][j] = __builtin_amdgcn_mfma_f32_16x16x32_bf16(a1[ks], b, acc[1][j], 0, 0, 0);
      }
    }
  }
  #pragma unroll
  for (int m=0; m<2; ++m){
    #pragma unroll
    for (int rr=0; rr<4; ++rr){
      int nw = wv*32 + m*16 + kq*4 + rr;
      if (nw < nN){
        #pragma unroll
        for (int j=0; j<3; ++j){
          int col = j*16 + clo;
          if (col < 40) out[(size_t)nw*40 + col] = acc[m][j][rr] + bias[col];
        }
      }
    }
  }
}

// ---------------- GCN aggregation: sum of pre-scaled bf16 rows, x disp[n] ----------------
__device__ __forceinline__ void acc_bf2(unsigned u, float& ax, float& ay){
  ax += __uint_as_float(u << 16);
  ay += __uint_as_float(u & 0xffff0000u);
}

__global__ __launch_bounds__(TPB) void gcn_k(const u16* __restrict__ hs, const int* __restrict__ rowptr,
                                             const int* __restrict__ csr, const float* __restrict__ disp,
                                             float* __restrict__ outb, int nN){
  int g = blockIdx.x*TPB + threadIdx.x;
  int n = g >> 6, lane = g & 63;
  if (n >= nN) return;
  const unsigned* H = (const unsigned*)hs;    // 64 dwords per row (128 bf16)
  int e0 = rowptr[n], e1 = rowptr[n+1];
  float ax=0.f, ay=0.f;
  int e = e0;
  for (; e + 4 <= e1; e += 4){
    int s0 = csr[e], s1 = csr[e+1], s2 = csr[e+2], s3 = csr[e+3];
    unsigned u0 = H[(size_t)s0*64 + lane];
    unsigned u1 = H[(size_t)s1*64 + lane];
    unsigned u2 = H[(size_t)s2*64 + lane];
    unsigned u3 = H[(size_t)s3*64 + lane];
    acc_bf2(u0, ax, ay); acc_bf2(u1, ax, ay);
    acc_bf2(u2, ax, ay); acc_bf2(u3, ax, ay);
  }
  for (; e < e1; ++e){
    unsigned u = H[(size_t)csr[e]*64 + lane];
    acc_bf2(u, ax, ay);
  }
  unsigned un = H[(size_t)n*64 + lane];        // self-loop (hs already has dis[n] factor)
  acc_bf2(un, ax, ay);
  float dn = disp[n];
  float2 r2; r2.x = ax*dn; r2.y = ay*dn;
  *(float2*)(outb + (size_t)n*384 + 2*lane) = r2;
}

// ---------------- BatchNorm ----------------
__global__ __launch_bounds__(TPB) void bn_stat_k(const float* __restrict__ hb, float* __restrict__ stats, int nN){
  int col  = threadIdx.x & 127;
  int half = threadIdx.x >> 7;
  float s=0.f, sq=0.f;
  for (int r = blockIdx.x*2 + half; r < nN; r += gridDim.x*2){
    float v = hb[(size_t)r*384 + col];
    s += v; sq += v*v;
  }
  __shared__ float ls[TPB], lq[TPB];
  ls[threadIdx.x]=s; lq[threadIdx.x]=sq;
  __syncthreads();
  if (half==0){
    s  = ls[threadIdx.x] + ls[threadIdx.x+128];
    sq = lq[threadIdx.x] + lq[threadIdx.x+128];
    atomicAdd(&stats[col], s);
    atomicAdd(&stats[128+col], sq);
  }
}

__global__ void bn_fin_k(const float* __restrict__ stats, const float* __restrict__ g, const float* __restrict__ b,
                         float* __restrict__ scsh, int nN){
  int c = threadIdx.x;
  float inv = 1.f/(float)nN;
  float m = stats[c]*inv;
  float var = fmaxf(stats[128+c]*inv - m*m, 0.f);
  float sc = g[c]*rsqrtf(var + 1e-5f);
  scsh[c] = sc;
  scsh[128+c] = b[c] - m*sc;
}

__global__ __launch_bounds__(TPB) void bn_apply_k(float* __restrict__ hb, const float* __restrict__ scsh, int nN){
  int idx = blockIdx.x*TPB + threadIdx.x;
  if (idx >= nN*128) return;
  int n = idx >> 7, c = idx & 127;
  float* p = hb + (size_t)n*384 + c;
  *p = fmaf(*p, scsh[c], scsh[128+c]);
}

extern "C" void kernel_launch(void* const* d_in, const int* in_sizes, int n_in,
                              void* d_out, int out_size, void* d_ws, size_t ws_size,
                              hipStream_t stream)
{
  const float* x        = (const float*)d_in[0];
  const int*   ei       = (const int*)d_in[1];
  const float* ln_g     = (const float*)d_in[2];
  const float* ln_b     = (const float*)d_in[3];
  const float* sw       = (const float*)d_in[4];
  const float* bw       = (const float*)d_in[5];
  const float* bb       = (const float*)d_in[6];
  // d_in[7] gcn_bias: canceled exactly by BatchNorm mean subtraction. Skipped.
  const float* bn_g     = (const float*)d_in[8];
  const float* bn_b     = (const float*)d_in[9];
  const float* ln_g_out = (const float*)d_in[10];
  const float* ln_b_out = (const float*)d_in[11];
  const float* sw_out   = (const float*)d_in[12];
  const float* bw_out   = (const float*)d_in[13];
  const float* bb_out   = (const float*)d_in[14];
  float* out = (float*)d_out;

  const int nN = in_sizes[0] / 128;    // 50000
  const int E  = in_sizes[1] / 2;      // 800000

  char* ws = (char*)d_ws;
  size_t off = 0;
  auto alloc = [&](size_t bytes)->char*{
    char* p = ws + off; off = (off + bytes + 255) & ~size_t(255); return p;
  };
  float* hbuf  = (float*)alloc((size_t)nN*384*4);   // [N, 3*128] BN outputs (concat tail)
  u16*   hs    = (u16*)alloc((size_t)nN*128*2);     // pre-scaled bf16 FKAN output (GCN input)
  float* meanp = (float*)alloc((size_t)nN*4);
  float* rstdp = (float*)alloc((size_t)nN*4);
  float* disp  = (float*)alloc((size_t)nN*4);
  float* stats = (float*)alloc(256*4);
  float* scsh  = (float*)alloc(256*4);
  u16*   wpre  = (u16*)alloc((size_t)3*80*512*2);
  int* cnt     = (int*)alloc((size_t)nN*4);
  int* cursor  = (int*)alloc((size_t)nN*4);
  int* rowptr  = (int*)alloc((size_t)(nN+1)*4);
  int* bsum    = (int*)alloc(256*4);
  int* csr     = (int*)alloc((size_t)E*4);
  (void)ws_size; (void)n_in; (void)out_size;

  const int* srcE = ei;
  const int* dstE = ei + E;

  hipMemsetAsync(cnt, 0, (size_t)nN*4, stream);
  hipMemsetAsync(cursor, 0, (size_t)nN*4, stream);

  const int nbE = (E + TPB-1)/TPB;
  const int nbN = (nN + TPB-1)/TPB;
  count_k<<<nbE, TPB, 0, stream>>>(dstE, cnt, E);
  dis_k<<<nbN, TPB, 0, stream>>>(cnt, disp, nN);
  scan1_k<<<nbN, TPB, 0, stream>>>(cnt, rowptr, bsum, nN);
  scan2_k<<<1, TPB, 0, stream>>>(bsum, nbN);
  scan3_k<<<nbN, TPB, 0, stream>>>(rowptr, bsum, nN, E);
  fill_k<<<nbE, TPB, 0, stream>>>(srcE, dstE, rowptr, cursor, csr, E);

  const int nbW = (nN*64 + TPB-1)/TPB;                  // wave-per-node kernels
  const int nbL = (((nN + 15)/16) + 3)/4;               // fkan layer: 16 nodes/wave, 4 waves/block
  const int nbO = (((nN + 31)/32) + 3)/4;               // fkan out: 32 nodes/wave

  for (int i=0; i<3; ++i){
    const float* inbase = (i==0) ? x : (hbuf + (size_t)(i-1)*128);
    int instride = (i==0) ? 128 : 384;
    prep_wpre_k<<<(8*20*512 + TPB-1)/TPB, TPB, 0, stream>>>(
        sw + (size_t)i*128*512, bw + (size_t)i*128*128, wpre, 128, 20, 8, 128);
    fkan_layer_k<<<nbL, TPB, 0, stream>>>(
        inbase, instride, ln_g + (size_t)i*128, ln_b + (size_t)i*128,
        wpre, bb + (size_t)i*128, disp, hs, nN);
    gcn_k<<<nbW, TPB, 0, stream>>>(hs, rowptr, csr, disp, hbuf + (size_t)i*128, nN);
    hipMemsetAsync(stats, 0, 256*4, stream);
    bn_stat_k<<<256, TPB, 0, stream>>>(hbuf + (size_t)i*128, stats, nN);
    bn_fin_k<<<1, 128, 0, stream>>>(stats, bn_g + (size_t)i*128, bn_b + (size_t)i*128, scsh, nN);
    bn_apply_k<<<(nN*128 + TPB-1)/TPB, TPB, 0, stream>>>(hbuf + (size_t)i*128, scsh, nN);
  }

  // final FKAN on concat [x | hbuf]  (512 -> 40)
  ln512_k<<<nbW, TPB, 0, stream>>>(x, hbuf, meanp, rstdp, nN);
  prep_wpre_k<<<(3*80*512 + TPB-1)/TPB, TPB, 0, stream>>>(
      sw_out, bw_out, wpre, 512, 80, 3, 40);
  fkan_out_k<<<nbO, TPB, 0, stream>>>(
      x, hbuf, meanp, rstdp, ln_g_out, ln_b_out, wpre, bb_out, out, nN);
}